// Round 11
// baseline (759.403 us; speedup 1.0000x reference)
//
#include <hip/hip_runtime.h>
#include <cstdint>

#define NN 50000
#define NE 600000
#define NGR 256
#define HD 128
#define HD2 64            // bf16x2 packed words per row
#define BN_EPS 1e-5f

typedef __attribute__((ext_vector_type(8))) short bf16x8;
typedef __attribute__((ext_vector_type(4))) float f32x4;

// ---- bf16 pack/unpack (bit ops; values are normal floats, no inf/nan) ----
static __device__ __forceinline__ unsigned f2bf(float f) {
  unsigned u = __float_as_uint(f);
  return (u + 0x7FFFu + ((u >> 16) & 1u)) >> 16;   // round-to-nearest-even
}
static __device__ __forceinline__ float bf_lo(unsigned v) {
  return __uint_as_float(v << 16);
}
static __device__ __forceinline__ float bf_hi(unsigned v) {
  return __uint_as_float(v & 0xFFFF0000u);
}

// ---------------- zero scratch accumulators ----------------
__global__ void k_zero(float4* __restrict__ p, int n4) {
  int i = blockIdx.x * blockDim.x + threadIdx.x;
  if (i < n4) p[i] = make_float4(0.f, 0.f, 0.f, 0.f);
}

// ---------------- in-degree count ----------------
__global__ void k_count(const int* __restrict__ dst, int* __restrict__ cnt) {
  int i = blockIdx.x * blockDim.x + threadIdx.x;
  if (i < NE) atomicAdd(&cnt[dst[i]], 1);
}

// ---------------- per-graph node count (histogram of batch; replaces MODE1 gcnt atomics) ----
__global__ void k_bcount(const int* __restrict__ batch, float* __restrict__ gcnt) {
  int i = blockIdx.x * blockDim.x + threadIdx.x;
  if (i < NN) atomicAdd(&gcnt[batch[i]], 1.0f);
}

// ---------------- CSR row-ptr scan (3 phases) ----------------
__global__ __launch_bounds__(1024) void k_scan1(const int* __restrict__ cnt,
                                                int* __restrict__ rowptr,
                                                int* __restrict__ aux,
                                                float* __restrict__ dis) {
  __shared__ int sd[1024];
  int tid = threadIdx.x;
  int i = blockIdx.x * 1024 + tid;
  int v = (i < NN) ? cnt[i] : 0;
  if (i < NN) dis[i] = 1.0f / sqrtf((float)v + 1.0f);
  sd[tid] = v;
  __syncthreads();
  for (int off = 1; off < 1024; off <<= 1) {
    int t = (tid >= off) ? sd[tid - off] : 0;
    __syncthreads();
    sd[tid] += t;
    __syncthreads();
  }
  if (i < NN) rowptr[i + 1] = sd[tid];
  if (tid == 1023) aux[blockIdx.x] = sd[1023];
}

__global__ void k_scan2(const int* __restrict__ aux, int* __restrict__ auxsc, int nchunks) {
  if (threadIdx.x == 0 && blockIdx.x == 0) {
    int run = 0;
    for (int c = 0; c < nchunks; ++c) { auxsc[c] = run; run += aux[c]; }
  }
}

__global__ void k_scan3(int* __restrict__ rowptr, const int* __restrict__ auxsc) {
  int i = blockIdx.x * blockDim.x + threadIdx.x;
  if (i < NN) rowptr[i + 1] += auxsc[i >> 10];
  if (i == 0) rowptr[0] = 0;
}

__global__ void k_fill(const int* __restrict__ src, const int* __restrict__ dst,
                       const int* __restrict__ rowptr, int* __restrict__ fillp,
                       int* __restrict__ colidx) {
  int i = blockIdx.x * blockDim.x + threadIdx.x;
  if (i < NE) {
    int d = dst[i];
    int p = rowptr[d] + atomicAdd(&fillp[d], 1);
    colidx[p] = src[i];
  }
}

// ---------------- W^T precompute: WT[n][k] = bf16(W[k][n]) ----------------
__global__ void k_wt(const float* __restrict__ W, unsigned short* __restrict__ WT) {
  int idx = blockIdx.x * 256 + threadIdx.x;   // 16384
  int k = idx >> 7, n = idx & 127;
  WT[n * 128 + k] = (unsigned short)f2bf(W[idx]);
}

// ---------------- MFMA GEMM: HS(bf16x2) = dis * (act(X) @ W) ----------------
// Swapped operands: D[n][m] = sum_k WT[n][k] * X[m][k]. Tile M=128 x N=128 x K=128.
// 4 waves; wave w owns m-rows [32w, 32w+32) as two 16-row blocks. 64 mfma/wave.
// LDS chunk-swizzle: 16B chunk c of row r at c ^ (r&15) -> reads 2-way (free).
template<bool BN>
__global__ __launch_bounds__(256) void k_gemm(
    const void* __restrict__ Xv, const unsigned short* __restrict__ WT,
    const float* __restrict__ scale, const float* __restrict__ shift,
    const float* __restrict__ dis, unsigned* __restrict__ HS) {
  __shared__ unsigned short lw[128 * 128];   // WT tile [n][k]  32KB
  __shared__ unsigned short lx[128 * 128];   // X tile  [m][k]  32KB
  int tid = threadIdx.x;
  int row0 = blockIdx.x * 128;
  // stage WT -> lw (swizzled)
#pragma unroll
  for (int i = 0; i < 8; ++i) {
    int c2 = tid + 256 * i;                  // 2048 chunks = 128 rows x 16
    int n = c2 >> 4, c = c2 & 15;
    uint4 v = *(const uint4*)&WT[n * 128 + c * 8];
    *(uint4*)&lw[n * 128 + ((c ^ (n & 15)) << 3)] = v;
  }
  // stage X -> lx (convert + optional BN/ReLU, swizzled)
#pragma unroll
  for (int i = 0; i < 8; ++i) {
    int c2 = tid + 256 * i;                  // 2048 chunks = 128 rows x 16
    int m = c2 >> 4, c = c2 & 15;
    int row = row0 + m;
    unsigned short h[8];
    if (row < NN) {
      if constexpr (!BN) {
        const float* X = (const float*)Xv;
        const float* xp = &X[(size_t)row * HD + c * 8];
        float4 a0 = *(const float4*)xp;
        float4 a1 = *(const float4*)(xp + 4);
        h[0] = (unsigned short)f2bf(a0.x); h[1] = (unsigned short)f2bf(a0.y);
        h[2] = (unsigned short)f2bf(a0.z); h[3] = (unsigned short)f2bf(a0.w);
        h[4] = (unsigned short)f2bf(a1.x); h[5] = (unsigned short)f2bf(a1.y);
        h[6] = (unsigned short)f2bf(a1.z); h[7] = (unsigned short)f2bf(a1.w);
      } else {
        const unsigned* X = (const unsigned*)Xv;      // packed bf16 AGG
        uint4 pw = *(const uint4*)&X[(size_t)row * HD2 + c * 4];
        float4 sc0 = *(const float4*)&scale[c * 8];
        float4 sc1 = *(const float4*)&scale[c * 8 + 4];
        float4 sh0 = *(const float4*)&shift[c * 8];
        float4 sh1 = *(const float4*)&shift[c * 8 + 4];
        h[0] = (unsigned short)f2bf(fmaxf(fmaf(sc0.x, bf_lo(pw.x), sh0.x), 0.f));
        h[1] = (unsigned short)f2bf(fmaxf(fmaf(sc0.y, bf_hi(pw.x), sh0.y), 0.f));
        h[2] = (unsigned short)f2bf(fmaxf(fmaf(sc0.z, bf_lo(pw.y), sh0.z), 0.f));
        h[3] = (unsigned short)f2bf(fmaxf(fmaf(sc0.w, bf_hi(pw.y), sh0.w), 0.f));
        h[4] = (unsigned short)f2bf(fmaxf(fmaf(sc1.x, bf_lo(pw.z), sh1.x), 0.f));
        h[5] = (unsigned short)f2bf(fmaxf(fmaf(sc1.y, bf_hi(pw.z), sh1.y), 0.f));
        h[6] = (unsigned short)f2bf(fmaxf(fmaf(sc1.z, bf_lo(pw.w), sh1.z), 0.f));
        h[7] = (unsigned short)f2bf(fmaxf(fmaf(sc1.w, bf_hi(pw.w), sh1.w), 0.f));
      }
    } else {
#pragma unroll
      for (int j = 0; j < 8; ++j) h[j] = 0;
    }
    *(uint4*)&lx[m * 128 + ((c ^ (m & 15)) << 3)] = *(uint4*)h;
  }
  __syncthreads();

  int l = tid & 63, w = tid >> 6;
  int cl = l & 15, g = l >> 4;
  f32x4 acc[2][8];
#pragma unroll
  for (int mb = 0; mb < 2; ++mb)
#pragma unroll
    for (int nb = 0; nb < 8; ++nb)
#pragma unroll
      for (int z = 0; z < 4; ++z) acc[mb][nb][z] = 0.f;

#pragma unroll
  for (int ks = 0; ks < 4; ++ks) {
    int chunk = ((ks * 4 + g) ^ cl) << 3;
    bf16x8 b0 = *(bf16x8*)&lx[(w * 32 + cl) * 128 + chunk];
    bf16x8 b1 = *(bf16x8*)&lx[(w * 32 + 16 + cl) * 128 + chunk];
#pragma unroll
    for (int nb = 0; nb < 8; ++nb) {
      bf16x8 a = *(bf16x8*)&lw[(nb * 16 + cl) * 128 + chunk];
      acc[0][nb] = __builtin_amdgcn_mfma_f32_16x16x32_bf16(a, b0, acc[0][nb], 0, 0, 0);
      acc[1][nb] = __builtin_amdgcn_mfma_f32_16x16x32_bf16(a, b1, acc[1][nb], 0, 0, 0);
    }
  }
  // D[n][m]: lane cl = m-col, acc row = n. Pack pairs -> HS[m][n/2].
#pragma unroll
  for (int mb = 0; mb < 2; ++mb) {
    int m = row0 + w * 32 + mb * 16 + cl;
    if (m < NN) {
      float dv = dis[m];
#pragma unroll
      for (int nb = 0; nb < 8; ++nb) {
        unsigned w0 = (f2bf(acc[mb][nb][1] * dv) << 16) | f2bf(acc[mb][nb][0] * dv);
        unsigned w1 = (f2bf(acc[mb][nb][3] * dv) << 16) | f2bf(acc[mb][nb][2] * dv);
        *(uint2*)&HS[(size_t)m * HD2 + nb * 8 + g * 2] = make_uint2(w0, w1);
      }
    }
  }
}

// ---------------- aggregation (CSR gather, bf16x2 rows; int4 colidx) ----------------
// MODE 0: v = dis[i]*(sum HS[src] + HS[i]) + b ; write packed bf16 AGG; BN stats
// MODE 1: v = relu(same); per-node dot(v, Wl) pooled per graph (gsum only)
template<int MODE>
__global__ __launch_bounds__(256) void k_agg(
    const unsigned* __restrict__ HS, const float* __restrict__ dis,
    const int* __restrict__ rowptr, const int* __restrict__ colidx,
    const float* __restrict__ bias,
    unsigned* __restrict__ AGG, float* __restrict__ stats,
    const int* __restrict__ batch, const float* __restrict__ Wl,
    float* __restrict__ gsum) {
  __shared__ float red[4][128];
  int tid = threadIdx.x;
  int lane = tid & 63;
  int wv = tid >> 6;        // wave id 0..3, one node per wave per iter
  int c0 = lane * 2;        // this lane's two channels (one packed word)
  float b0 = bias[c0], b1 = bias[c0 + 1];
  float wl0 = 0.f, wl1 = 0.f;
  if (MODE == 1) { wl0 = Wl[c0]; wl1 = Wl[c0 + 1]; }
  float ssum0 = 0.f, ssum1 = 0.f, ssq0 = 0.f, ssq1 = 0.f;
  int stride = gridDim.x * 4;
  for (int i = blockIdx.x * 4 + wv; i < NN; i += stride) {
    unsigned sv = HS[(size_t)i * HD2 + lane];
    float ax = bf_lo(sv), ay = bf_hi(sv);  // self-loop term (HS pre-scaled by dis)
    float bx = 0.f, by = 0.f;              // 4 accumulator chains
    float cx = 0.f, cy = 0.f;
    float dx = 0.f, dy = 0.f;
    int e0 = rowptr[i], e1 = rowptr[i + 1];
    int e = e0;
    // peel to 16B alignment of colidx
    for (; e < e1 && (e & 3); ++e) {
      unsigned h0 = HS[(size_t)colidx[e] * HD2 + lane];
      ax += bf_lo(h0); ay += bf_hi(h0);
    }
    // 8-edge unroll, index loads as 2x int4 (1 instr per 4 edges)
    for (; e + 7 < e1; e += 8) {
      int4 ca = *(const int4*)&colidx[e];
      int4 cb = *(const int4*)&colidx[e + 4];
      unsigned h0 = HS[(size_t)ca.x * HD2 + lane];
      unsigned h1 = HS[(size_t)ca.y * HD2 + lane];
      unsigned h2 = HS[(size_t)ca.z * HD2 + lane];
      unsigned h3 = HS[(size_t)ca.w * HD2 + lane];
      unsigned h4 = HS[(size_t)cb.x * HD2 + lane];
      unsigned h5 = HS[(size_t)cb.y * HD2 + lane];
      unsigned h6 = HS[(size_t)cb.z * HD2 + lane];
      unsigned h7 = HS[(size_t)cb.w * HD2 + lane];
      ax += bf_lo(h0); ay += bf_hi(h0);
      bx += bf_lo(h1); by += bf_hi(h1);
      cx += bf_lo(h2); cy += bf_hi(h2);
      dx += bf_lo(h3); dy += bf_hi(h3);
      ax += bf_lo(h4); ay += bf_hi(h4);
      bx += bf_lo(h5); by += bf_hi(h5);
      cx += bf_lo(h6); cy += bf_hi(h6);
      dx += bf_lo(h7); dy += bf_hi(h7);
    }
    for (; e + 3 < e1; e += 4) {
      int4 ca = *(const int4*)&colidx[e];
      unsigned h0 = HS[(size_t)ca.x * HD2 + lane];
      unsigned h1 = HS[(size_t)ca.y * HD2 + lane];
      unsigned h2 = HS[(size_t)ca.z * HD2 + lane];
      unsigned h3 = HS[(size_t)ca.w * HD2 + lane];
      ax += bf_lo(h0); ay += bf_hi(h0);
      bx += bf_lo(h1); by += bf_hi(h1);
      cx += bf_lo(h2); cy += bf_hi(h2);
      dx += bf_lo(h3); dy += bf_hi(h3);
    }
    for (; e < e1; ++e) {
      unsigned h0 = HS[(size_t)colidx[e] * HD2 + lane];
      ax += bf_lo(h0); ay += bf_hi(h0);
    }
    float di = dis[i];
    float vx = fmaf(di, (ax + bx) + (cx + dx), b0);
    float vy = fmaf(di, (ay + by) + (cy + dy), b1);
    if (MODE == 0) {
      AGG[(size_t)i * HD2 + lane] = (f2bf(vy) << 16) | f2bf(vx);
      ssum0 += vx; ssum1 += vy;
      ssq0 = fmaf(vx, vx, ssq0);
      ssq1 = fmaf(vy, vy, ssq1);
    } else {
      vx = fmaxf(vx, 0.f);
      vy = fmaxf(vy, 0.f);
      float p = vx * wl0 + vy * wl1;
#pragma unroll
      for (int m = 32; m >= 1; m >>= 1) p += __shfl_xor(p, m);
      if (lane == 0) atomicAdd(&gsum[batch[i]], p);
    }
  }
  if (MODE == 0) {
    red[wv][c0] = ssum0; red[wv][c0 + 1] = ssum1;
    __syncthreads();
    if (wv == 0) {
      float t0 = red[0][c0] + red[1][c0] + red[2][c0] + red[3][c0];
      float t1 = red[0][c0 + 1] + red[1][c0 + 1] + red[2][c0 + 1] + red[3][c0 + 1];
      atomicAdd(&stats[c0], t0);
      atomicAdd(&stats[c0 + 1], t1);
    }
    __syncthreads();
    red[wv][c0] = ssq0; red[wv][c0 + 1] = ssq1;
    __syncthreads();
    if (wv == 0) {
      float q0 = red[0][c0] + red[1][c0] + red[2][c0] + red[3][c0];
      float q1 = red[0][c0 + 1] + red[1][c0 + 1] + red[2][c0 + 1] + red[3][c0 + 1];
      atomicAdd(&stats[HD + c0], q0);
      atomicAdd(&stats[HD + c0 + 1], q1);
    }
  }
}

// ---------------- BN finalize: per-channel scale/shift ----------------
__global__ void k_bnfin(const float* __restrict__ stats, const float* __restrict__ gamma,
                        const float* __restrict__ beta, float* __restrict__ scale,
                        float* __restrict__ shift) {
  int c = threadIdx.x;
  float inv_n = 1.0f / (float)NN;
  float mean = stats[c] * inv_n;
  float var = stats[HD + c] * inv_n - mean * mean;
  float s = gamma[c] / sqrtf(var + BN_EPS);
  scale[c] = s;
  shift[c] = fmaf(-mean, s, beta[c]);
}

// ---------------- final: mean-pool divide + bias ----------------
__global__ void k_final(const float* __restrict__ gsum, const float* __restrict__ gcnt,
                        const float* __restrict__ bl, float* __restrict__ out) {
  int g = threadIdx.x;
  out[g] = gsum[g] / fmaxf(gcnt[g], 1.0f) + bl[0];
}

extern "C" void kernel_launch(void* const* d_in, const int* in_sizes, int n_in,
                              void* d_out, int out_size, void* d_ws, size_t ws_size,
                              hipStream_t stream) {
  (void)in_sizes; (void)n_in; (void)out_size; (void)ws_size;
  const float* x   = (const float*)d_in[0];
  const int* ei    = (const int*)d_in[1];
  const int* batch = (const int*)d_in[2];
  const float* W1  = (const float*)d_in[3];
  const float* b1  = (const float*)d_in[4];
  const float* g1  = (const float*)d_in[5];
  const float* be1 = (const float*)d_in[6];
  const float* W2  = (const float*)d_in[7];
  const float* b2  = (const float*)d_in[8];
  const float* g2  = (const float*)d_in[9];
  const float* be2 = (const float*)d_in[10];
  const float* W3  = (const float*)d_in[11];
  const float* b3  = (const float*)d_in[12];
  const float* Wl  = (const float*)d_in[13];
  const float* bl  = (const float*)d_in[14];
  float* out = (float*)d_out;

  const int* srcv = ei;        // edge_index[0]
  const int* dstv = ei + NE;   // edge_index[1]

  // ---- workspace layout (all offsets 16B-aligned) ----
  unsigned* hs   = (unsigned*)d_ws;                 // [NN][HD2] bf16x2
  unsigned* aggb = hs + (size_t)NN * HD2;           // [NN][HD2] bf16x2
  float* dis     = (float*)(aggb + (size_t)NN * HD2);  // [NN]
  int*   rowptr  = (int*)(dis + NN);                // [NN+1] (padded to NN+4)
  int*   colidx  = rowptr + (NN + 4);               // [NE], 16B-aligned
  unsigned short* wtb = (unsigned short*)(colidx + NE);  // [128*128] bf16 W^T
  float* scale1  = (float*)(wtb + 128 * 128);
  float* shift1  = scale1 + HD;
  float* scale2  = shift1 + HD;
  float* shift2  = scale2 + HD;
  float* zbase   = shift2 + HD;                     // ---- zeroed region start ----
  int*   degc    = (int*)zbase;                     // [NN]
  int*   fillp   = degc + NN;                       // [NN]
  int*   aux     = fillp + NN;                      // [64]
  int*   auxsc   = aux + 64;                        // [64]
  float* stats1  = (float*)(auxsc + 64);            // [256]
  float* stats2  = stats1 + 2 * HD;                 // [256]
  float* gsum    = stats2 + 2 * HD;                 // [256]
  float* gcnt    = gsum + NGR;                      // [256]
  float* zend    = gcnt + NGR;
  int n4 = (int)(((char*)zend - (char*)zbase) / 16);

  k_zero<<<(n4 + 255) / 256, 256, 0, stream>>>((float4*)zbase, n4);

  // CSR build (once; reused by all 3 layers) + per-graph counts
  k_count<<<(NE + 255) / 256, 256, 0, stream>>>(dstv, degc);
  k_bcount<<<(NN + 255) / 256, 256, 0, stream>>>(batch, gcnt);
  int nchunk = (NN + 1023) / 1024;
  k_scan1<<<nchunk, 1024, 0, stream>>>(degc, rowptr, aux, dis);
  k_scan2<<<1, 1, 0, stream>>>(aux, auxsc, nchunk);
  k_scan3<<<(NN + 255) / 256, 256, 0, stream>>>(rowptr, auxsc);
  k_fill<<<(NE + 255) / 256, 256, 0, stream>>>(srcv, dstv, rowptr, fillp, colidx);

  int gblk = (NN + 127) / 128;   // 391
  // layer 1
  k_wt<<<64, 256, 0, stream>>>(W1, wtb);
  k_gemm<false><<<gblk, 256, 0, stream>>>(x, wtb, nullptr, nullptr, dis, hs);
  k_agg<0><<<2048, 256, 0, stream>>>(hs, dis, rowptr, colidx, b1, aggb, stats1,
                                     nullptr, nullptr, nullptr);
  k_bnfin<<<1, HD, 0, stream>>>(stats1, g1, be1, scale1, shift1);
  // layer 2
  k_wt<<<64, 256, 0, stream>>>(W2, wtb);
  k_gemm<true><<<gblk, 256, 0, stream>>>(aggb, wtb, scale1, shift1, dis, hs);
  k_agg<0><<<2048, 256, 0, stream>>>(hs, dis, rowptr, colidx, b2, aggb, stats2,
                                     nullptr, nullptr, nullptr);
  k_bnfin<<<1, HD, 0, stream>>>(stats2, g2, be2, scale2, shift2);
  // layer 3 (BN+ReLU fused into GEMM staging; pool+linear fused into agg)
  k_wt<<<64, 256, 0, stream>>>(W3, wtb);
  k_gemm<true><<<gblk, 256, 0, stream>>>(aggb, wtb, scale2, shift2, dis, hs);
  k_agg<1><<<2048, 256, 0, stream>>>(hs, dis, rowptr, colidx, b3, nullptr, nullptr,
                                     batch, Wl, gsum);
  k_final<<<1, NGR, 0, stream>>>(gsum, gcnt, bl, out);
}

// Round 12
// 710.976 us; speedup vs baseline: 1.0681x; 1.0681x over previous
//
#include <hip/hip_runtime.h>
#include <cstdint>

#define NN 50000
#define NE 600000
#define NGR 256
#define HD 128
#define HD2 64            // bf16x2 packed words per row
#define BN_EPS 1e-5f

typedef __attribute__((ext_vector_type(8))) short bf16x8;
typedef __attribute__((ext_vector_type(4))) float f32x4;

// ---- bf16 pack/unpack (bit ops; values are normal floats, no inf/nan) ----
static __device__ __forceinline__ unsigned f2bf(float f) {
  unsigned u = __float_as_uint(f);
  return (u + 0x7FFFu + ((u >> 16) & 1u)) >> 16;   // round-to-nearest-even
}
static __device__ __forceinline__ float bf_lo(unsigned v) {
  return __uint_as_float(v << 16);
}
static __device__ __forceinline__ float bf_hi(unsigned v) {
  return __uint_as_float(v & 0xFFFF0000u);
}

// ---------------- zero scratch accumulators ----------------
__global__ void k_zero(float4* __restrict__ p, int n4) {
  int i = blockIdx.x * blockDim.x + threadIdx.x;
  if (i < n4) p[i] = make_float4(0.f, 0.f, 0.f, 0.f);
}

// ---------------- in-degree count ----------------
__global__ void k_count(const int* __restrict__ dst, int* __restrict__ cnt) {
  int i = blockIdx.x * blockDim.x + threadIdx.x;
  if (i < NE) atomicAdd(&cnt[dst[i]], 1);
}

// ---------------- per-graph node count (hoisted out of MODE1 agg) ----------------
__global__ void k_bcount(const int* __restrict__ batch, float* __restrict__ gcnt) {
  int i = blockIdx.x * blockDim.x + threadIdx.x;
  if (i < NN) atomicAdd(&gcnt[batch[i]], 1.0f);
}

// ---------------- CSR row-ptr scan (3 phases) ----------------
__global__ __launch_bounds__(1024) void k_scan1(const int* __restrict__ cnt,
                                                int* __restrict__ rowptr,
                                                int* __restrict__ aux,
                                                float* __restrict__ dis) {
  __shared__ int sd[1024];
  int tid = threadIdx.x;
  int i = blockIdx.x * 1024 + tid;
  int v = (i < NN) ? cnt[i] : 0;
  if (i < NN) dis[i] = 1.0f / sqrtf((float)v + 1.0f);
  sd[tid] = v;
  __syncthreads();
  for (int off = 1; off < 1024; off <<= 1) {
    int t = (tid >= off) ? sd[tid - off] : 0;
    __syncthreads();
    sd[tid] += t;
    __syncthreads();
  }
  if (i < NN) rowptr[i + 1] = sd[tid];
  if (tid == 1023) aux[blockIdx.x] = sd[1023];
}

__global__ void k_scan2(const int* __restrict__ aux, int* __restrict__ auxsc, int nchunks) {
  if (threadIdx.x == 0 && blockIdx.x == 0) {
    int run = 0;
    for (int c = 0; c < nchunks; ++c) { auxsc[c] = run; run += aux[c]; }
  }
}

__global__ void k_scan3(int* __restrict__ rowptr, const int* __restrict__ auxsc) {
  int i = blockIdx.x * blockDim.x + threadIdx.x;
  if (i < NN) rowptr[i + 1] += auxsc[i >> 10];
  if (i == 0) rowptr[0] = 0;
}

__global__ void k_fill(const int* __restrict__ src, const int* __restrict__ dst,
                       const int* __restrict__ rowptr, int* __restrict__ fillp,
                       int* __restrict__ colidx) {
  int i = blockIdx.x * blockDim.x + threadIdx.x;
  if (i < NE) {
    int d = dst[i];
    int p = rowptr[d] + atomicAdd(&fillp[d], 1);
    colidx[p] = src[i];
  }
}

// ---------------- W^T precompute: WT[n][k] = bf16(W[k][n]) ----------------
__global__ void k_wt(const float* __restrict__ W, unsigned short* __restrict__ WT) {
  int idx = blockIdx.x * 256 + threadIdx.x;   // 16384
  int k = idx >> 7, n = idx & 127;
  WT[n * 128 + k] = (unsigned short)f2bf(W[idx]);
}

// ---------------- MFMA GEMM (r10 M=64 version): HS(bf16x2) = dis * (act(X) @ W) --------
// Swapped operands: D[n][m] = sum_k WT[n][k] * X[m][k]. Tile M=64 x N=128 x K=128.
// 4 waves; wave w owns m-rows [16w,16w+16). 782 blocks ~ 3/CU: balanced.
template<bool BN>
__global__ __launch_bounds__(256) void k_gemm(
    const void* __restrict__ Xv, const unsigned short* __restrict__ WT,
    const float* __restrict__ scale, const float* __restrict__ shift,
    const float* __restrict__ dis, unsigned* __restrict__ HS) {
  __shared__ unsigned short lw[128 * 128];   // WT tile  [n][k]
  __shared__ unsigned short lx[64 * 128];    // X tile   [m][k]
  int tid = threadIdx.x;
  int row0 = blockIdx.x * 64;
#pragma unroll
  for (int i = 0; i < 8; ++i) {
    int c2 = tid + 256 * i;                  // 2048 chunks = 128 rows x 16
    int n = c2 >> 4, c = c2 & 15;
    uint4 v = *(const uint4*)&WT[n * 128 + c * 8];
    *(uint4*)&lw[n * 128 + ((c ^ (n & 15)) << 3)] = v;
  }
#pragma unroll
  for (int i = 0; i < 4; ++i) {
    int c2 = tid + 256 * i;                  // 1024 chunks = 64 rows x 16
    int m = c2 >> 4, c = c2 & 15;
    int row = row0 + m;
    unsigned short h[8];
    if (row < NN) {
      if constexpr (!BN) {
        const float* X = (const float*)Xv;
        const float* xp = &X[(size_t)row * HD + c * 8];
        float4 a0 = *(const float4*)xp;
        float4 a1 = *(const float4*)(xp + 4);
        h[0] = (unsigned short)f2bf(a0.x); h[1] = (unsigned short)f2bf(a0.y);
        h[2] = (unsigned short)f2bf(a0.z); h[3] = (unsigned short)f2bf(a0.w);
        h[4] = (unsigned short)f2bf(a1.x); h[5] = (unsigned short)f2bf(a1.y);
        h[6] = (unsigned short)f2bf(a1.z); h[7] = (unsigned short)f2bf(a1.w);
      } else {
        const unsigned* X = (const unsigned*)Xv;      // packed bf16 AGG
        uint4 pw = *(const uint4*)&X[(size_t)row * HD2 + c * 4];
        float4 sc0 = *(const float4*)&scale[c * 8];
        float4 sc1 = *(const float4*)&scale[c * 8 + 4];
        float4 sh0 = *(const float4*)&shift[c * 8];
        float4 sh1 = *(const float4*)&shift[c * 8 + 4];
        h[0] = (unsigned short)f2bf(fmaxf(fmaf(sc0.x, bf_lo(pw.x), sh0.x), 0.f));
        h[1] = (unsigned short)f2bf(fmaxf(fmaf(sc0.y, bf_hi(pw.x), sh0.y), 0.f));
        h[2] = (unsigned short)f2bf(fmaxf(fmaf(sc0.z, bf_lo(pw.y), sh0.z), 0.f));
        h[3] = (unsigned short)f2bf(fmaxf(fmaf(sc0.w, bf_hi(pw.y), sh0.w), 0.f));
        h[4] = (unsigned short)f2bf(fmaxf(fmaf(sc1.x, bf_lo(pw.z), sh1.x), 0.f));
        h[5] = (unsigned short)f2bf(fmaxf(fmaf(sc1.y, bf_hi(pw.z), sh1.y), 0.f));
        h[6] = (unsigned short)f2bf(fmaxf(fmaf(sc1.z, bf_lo(pw.w), sh1.z), 0.f));
        h[7] = (unsigned short)f2bf(fmaxf(fmaf(sc1.w, bf_hi(pw.w), sh1.w), 0.f));
      }
    } else {
#pragma unroll
      for (int j = 0; j < 8; ++j) h[j] = 0;
    }
    *(uint4*)&lx[m * 128 + ((c ^ (m & 15)) << 3)] = *(uint4*)h;
  }
  __syncthreads();

  int l = tid & 63, w = tid >> 6;
  int cl = l & 15, g = l >> 4;
  f32x4 acc[8];
#pragma unroll
  for (int nb = 0; nb < 8; ++nb)
#pragma unroll
    for (int z = 0; z < 4; ++z) acc[nb][z] = 0.f;

#pragma unroll
  for (int ks = 0; ks < 4; ++ks) {
    int chunk = ((ks * 4 + g) ^ cl) << 3;
    bf16x8 b = *(bf16x8*)&lx[(w * 16 + cl) * 128 + chunk];
#pragma unroll
    for (int nb = 0; nb < 8; ++nb) {
      bf16x8 a = *(bf16x8*)&lw[(nb * 16 + cl) * 128 + chunk];
      acc[nb] = __builtin_amdgcn_mfma_f32_16x16x32_bf16(a, b, acc[nb], 0, 0, 0);
    }
  }
  int m = row0 + w * 16 + cl;
  if (m < NN) {
    float dv = dis[m];
#pragma unroll
    for (int nb = 0; nb < 8; ++nb) {
      unsigned w0 = (f2bf(acc[nb][1] * dv) << 16) | f2bf(acc[nb][0] * dv);
      unsigned w1 = (f2bf(acc[nb][3] * dv) << 16) | f2bf(acc[nb][2] * dv);
      *(uint2*)&HS[(size_t)m * HD2 + nb * 8 + g * 2] = make_uint2(w0, w1);
    }
  }
}

// ---------------- NEW: pair-agg — 2 nodes/wave, dwordx2/lane (layer 1 A/B arm) --------
// One gather instruction = both nodes' full 256B rows = 2 edges. Lines/edge unchanged.
__global__ __launch_bounds__(256) void k_aggp(
    const unsigned* __restrict__ HS, const float* __restrict__ dis,
    const int* __restrict__ rowptr, const int* __restrict__ colidx,
    const float* __restrict__ bias, unsigned* __restrict__ AGG,
    float* __restrict__ stats) {
  __shared__ float red[8][128];
  int tid = threadIdx.x;
  int lane = tid & 63;
  int wv = tid >> 6;
  int il = lane & 31;       // lane within half
  int half = lane >> 5;     // node slot within wave
  int c0 = il * 4;          // 4 channels per lane
  float4 bi = *(const float4*)&bias[c0];
  float s0 = 0.f, s1 = 0.f, s2 = 0.f, s3 = 0.f;
  float q0 = 0.f, q1 = 0.f, q2 = 0.f, q3 = 0.f;
  int stride = gridDim.x * 4;
  for (int p = blockIdx.x * 4 + wv; p < NN / 2; p += stride) {
    int n = p * 2 + half;
    int e0 = rowptr[n], e1 = rowptr[n + 1];
    int deg = e1 - e0;
    int m = max(deg, __shfl_xor(deg, 32));   // pair max degree
    uint2 sv = *(const uint2*)&HS[(size_t)n * HD2 + il * 2];
    float a0 = bf_lo(sv.x), a1 = bf_hi(sv.x);
    float a2 = bf_lo(sv.y), a3 = bf_hi(sv.y);
    float b0 = 0.f, b1 = 0.f, b2 = 0.f, b3 = 0.f;   // second chain
    int ecl = max(e1 - 1, 0);
    for (int k = 0; k < m; k += 2) {         // 2-deep: 2 row-loads (8 lines) in flight
      int eA = e0 + k, eB = e0 + k + 1;
      int iA = colidx[min(eA, ecl)];
      int iB = colidx[min(eB, ecl)];
      uint2 hA = *(const uint2*)&HS[(size_t)iA * HD2 + il * 2];
      uint2 hB = *(const uint2*)&HS[(size_t)iB * HD2 + il * 2];
      if (eA >= e1) { hA.x = 0u; hA.y = 0u; }   // bf16 zero -> add is no-op
      if (eB >= e1) { hB.x = 0u; hB.y = 0u; }
      a0 += bf_lo(hA.x); a1 += bf_hi(hA.x);
      a2 += bf_lo(hA.y); a3 += bf_hi(hA.y);
      b0 += bf_lo(hB.x); b1 += bf_hi(hB.x);
      b2 += bf_lo(hB.y); b3 += bf_hi(hB.y);
    }
    float di = dis[n];
    float v0 = fmaf(di, a0 + b0, bi.x);
    float v1 = fmaf(di, a1 + b1, bi.y);
    float v2 = fmaf(di, a2 + b2, bi.z);
    float v3 = fmaf(di, a3 + b3, bi.w);
    *(uint2*)&AGG[(size_t)n * HD2 + il * 2] =
        make_uint2((f2bf(v1) << 16) | f2bf(v0), (f2bf(v3) << 16) | f2bf(v2));
    s0 += v0; s1 += v1; s2 += v2; s3 += v3;
    q0 = fmaf(v0, v0, q0); q1 = fmaf(v1, v1, q1);
    q2 = fmaf(v2, v2, q2); q3 = fmaf(v3, v3, q3);
  }
  int r = wv * 2 + half;
  *(float4*)&red[r][c0] = make_float4(s0, s1, s2, s3);
  __syncthreads();
  if (tid < 128) {
    float s = 0.f;
#pragma unroll
    for (int r2 = 0; r2 < 8; ++r2) s += red[r2][tid];
    atomicAdd(&stats[tid], s);
  }
  __syncthreads();
  *(float4*)&red[r][c0] = make_float4(q0, q1, q2, q3);
  __syncthreads();
  if (tid < 128) {
    float s = 0.f;
#pragma unroll
    for (int r2 = 0; r2 < 8; ++r2) s += red[r2][tid];
    atomicAdd(&stats[HD + tid], s);
  }
}

// ---------------- OLD agg (r7 structure + int4 colidx) — layer-2 control & MODE-1 ------
template<int MODE>
__global__ __launch_bounds__(256) void k_agg(
    const unsigned* __restrict__ HS, const float* __restrict__ dis,
    const int* __restrict__ rowptr, const int* __restrict__ colidx,
    const float* __restrict__ bias,
    unsigned* __restrict__ AGG, float* __restrict__ stats,
    const int* __restrict__ batch, const float* __restrict__ Wl,
    float* __restrict__ gsum) {
  __shared__ float red[4][128];
  int tid = threadIdx.x;
  int lane = tid & 63;
  int wv = tid >> 6;
  int c0 = lane * 2;
  float b0 = bias[c0], b1 = bias[c0 + 1];
  float wl0 = 0.f, wl1 = 0.f;
  if (MODE == 1) { wl0 = Wl[c0]; wl1 = Wl[c0 + 1]; }
  float ssum0 = 0.f, ssum1 = 0.f, ssq0 = 0.f, ssq1 = 0.f;
  int stride = gridDim.x * 4;
  for (int i = blockIdx.x * 4 + wv; i < NN; i += stride) {
    unsigned sv = HS[(size_t)i * HD2 + lane];
    float ax = bf_lo(sv), ay = bf_hi(sv);
    float bx = 0.f, by = 0.f;
    float cx = 0.f, cy = 0.f;
    float dx = 0.f, dy = 0.f;
    int e0 = rowptr[i], e1 = rowptr[i + 1];
    int e = e0;
    for (; e < e1 && (e & 3); ++e) {
      unsigned h0 = HS[(size_t)colidx[e] * HD2 + lane];
      ax += bf_lo(h0); ay += bf_hi(h0);
    }
    for (; e + 7 < e1; e += 8) {
      int4 ca = *(const int4*)&colidx[e];
      int4 cb = *(const int4*)&colidx[e + 4];
      unsigned h0 = HS[(size_t)ca.x * HD2 + lane];
      unsigned h1 = HS[(size_t)ca.y * HD2 + lane];
      unsigned h2 = HS[(size_t)ca.z * HD2 + lane];
      unsigned h3 = HS[(size_t)ca.w * HD2 + lane];
      unsigned h4 = HS[(size_t)cb.x * HD2 + lane];
      unsigned h5 = HS[(size_t)cb.y * HD2 + lane];
      unsigned h6 = HS[(size_t)cb.z * HD2 + lane];
      unsigned h7 = HS[(size_t)cb.w * HD2 + lane];
      ax += bf_lo(h0); ay += bf_hi(h0);
      bx += bf_lo(h1); by += bf_hi(h1);
      cx += bf_lo(h2); cy += bf_hi(h2);
      dx += bf_lo(h3); dy += bf_hi(h3);
      ax += bf_lo(h4); ay += bf_hi(h4);
      bx += bf_lo(h5); by += bf_hi(h5);
      cx += bf_lo(h6); cy += bf_hi(h6);
      dx += bf_lo(h7); dy += bf_hi(h7);
    }
    for (; e + 3 < e1; e += 4) {
      int4 ca = *(const int4*)&colidx[e];
      unsigned h0 = HS[(size_t)ca.x * HD2 + lane];
      unsigned h1 = HS[(size_t)ca.y * HD2 + lane];
      unsigned h2 = HS[(size_t)ca.z * HD2 + lane];
      unsigned h3 = HS[(size_t)ca.w * HD2 + lane];
      ax += bf_lo(h0); ay += bf_hi(h0);
      bx += bf_lo(h1); by += bf_hi(h1);
      cx += bf_lo(h2); cy += bf_hi(h2);
      dx += bf_lo(h3); dy += bf_hi(h3);
    }
    for (; e < e1; ++e) {
      unsigned h0 = HS[(size_t)colidx[e] * HD2 + lane];
      ax += bf_lo(h0); ay += bf_hi(h0);
    }
    float di = dis[i];
    float vx = fmaf(di, (ax + bx) + (cx + dx), b0);
    float vy = fmaf(di, (ay + by) + (cy + dy), b1);
    if (MODE == 0) {
      AGG[(size_t)i * HD2 + lane] = (f2bf(vy) << 16) | f2bf(vx);
      ssum0 += vx; ssum1 += vy;
      ssq0 = fmaf(vx, vx, ssq0);
      ssq1 = fmaf(vy, vy, ssq1);
    } else {
      vx = fmaxf(vx, 0.f);
      vy = fmaxf(vy, 0.f);
      float p = vx * wl0 + vy * wl1;
#pragma unroll
      for (int m = 32; m >= 1; m >>= 1) p += __shfl_xor(p, m);
      if (lane == 0) atomicAdd(&gsum[batch[i]], p);
    }
  }
  if (MODE == 0) {
    red[wv][c0] = ssum0; red[wv][c0 + 1] = ssum1;
    __syncthreads();
    if (wv == 0) {
      float t0 = red[0][c0] + red[1][c0] + red[2][c0] + red[3][c0];
      float t1 = red[0][c0 + 1] + red[1][c0 + 1] + red[2][c0 + 1] + red[3][c0 + 1];
      atomicAdd(&stats[c0], t0);
      atomicAdd(&stats[c0 + 1], t1);
    }
    __syncthreads();
    red[wv][c0] = ssq0; red[wv][c0 + 1] = ssq1;
    __syncthreads();
    if (wv == 0) {
      float t0 = red[0][c0] + red[1][c0] + red[2][c0] + red[3][c0];
      float t1 = red[0][c0 + 1] + red[1][c0 + 1] + red[2][c0 + 1] + red[3][c0 + 1];
      atomicAdd(&stats[HD + c0], t0);
      atomicAdd(&stats[HD + c0 + 1], t1);
    }
  }
}

// ---------------- BN finalize: per-channel scale/shift ----------------
__global__ void k_bnfin(const float* __restrict__ stats, const float* __restrict__ gamma,
                        const float* __restrict__ beta, float* __restrict__ scale,
                        float* __restrict__ shift) {
  int c = threadIdx.x;
  float inv_n = 1.0f / (float)NN;
  float mean = stats[c] * inv_n;
  float var = stats[HD + c] * inv_n - mean * mean;
  float s = gamma[c] / sqrtf(var + BN_EPS);
  scale[c] = s;
  shift[c] = fmaf(-mean, s, beta[c]);
}

// ---------------- final: mean-pool divide + bias ----------------
__global__ void k_final(const float* __restrict__ gsum, const float* __restrict__ gcnt,
                        const float* __restrict__ bl, float* __restrict__ out) {
  int g = threadIdx.x;
  out[g] = gsum[g] / fmaxf(gcnt[g], 1.0f) + bl[0];
}

extern "C" void kernel_launch(void* const* d_in, const int* in_sizes, int n_in,
                              void* d_out, int out_size, void* d_ws, size_t ws_size,
                              hipStream_t stream) {
  (void)in_sizes; (void)n_in; (void)out_size; (void)ws_size;
  const float* x   = (const float*)d_in[0];
  const int* ei    = (const int*)d_in[1];
  const int* batch = (const int*)d_in[2];
  const float* W1  = (const float*)d_in[3];
  const float* b1  = (const float*)d_in[4];
  const float* g1  = (const float*)d_in[5];
  const float* be1 = (const float*)d_in[6];
  const float* W2  = (const float*)d_in[7];
  const float* b2  = (const float*)d_in[8];
  const float* g2  = (const float*)d_in[9];
  const float* be2 = (const float*)d_in[10];
  const float* W3  = (const float*)d_in[11];
  const float* b3  = (const float*)d_in[12];
  const float* Wl  = (const float*)d_in[13];
  const float* bl  = (const float*)d_in[14];
  float* out = (float*)d_out;

  const int* srcv = ei;        // edge_index[0]
  const int* dstv = ei + NE;   // edge_index[1]

  // ---- workspace layout (all offsets 16B-aligned) ----
  unsigned* hs   = (unsigned*)d_ws;                 // [NN][HD2] bf16x2
  unsigned* aggb = hs + (size_t)NN * HD2;           // [NN][HD2] bf16x2
  float* dis     = (float*)(aggb + (size_t)NN * HD2);  // [NN]
  int*   rowptr  = (int*)(dis + NN);                // [NN+1] (padded to NN+4)
  int*   colidx  = rowptr + (NN + 4);               // [NE], 16B-aligned
  unsigned short* wtb = (unsigned short*)(colidx + NE);  // [128*128] bf16 W^T
  float* scale1  = (float*)(wtb + 128 * 128);
  float* shift1  = scale1 + HD;
  float* scale2  = shift1 + HD;
  float* shift2  = scale2 + HD;
  float* zbase   = shift2 + HD;                     // ---- zeroed region start ----
  int*   degc    = (int*)zbase;                     // [NN]
  int*   fillp   = degc + NN;                       // [NN]
  int*   aux     = fillp + NN;                      // [64]
  int*   auxsc   = aux + 64;                        // [64]
  float* stats1  = (float*)(auxsc + 64);            // [256]
  float* stats2  = stats1 + 2 * HD;                 // [256]
  float* gsum    = stats2 + 2 * HD;                 // [256]
  float* gcnt    = gsum + NGR;                      // [256]
  float* zend    = gcnt + NGR;
  int n4 = (int)(((char*)zend - (char*)zbase) / 16);

  k_zero<<<(n4 + 255) / 256, 256, 0, stream>>>((float4*)zbase, n4);

  // CSR build (once; reused by all 3 layers) + per-graph counts
  k_count<<<(NE + 255) / 256, 256, 0, stream>>>(dstv, degc);
  k_bcount<<<(NN + 255) / 256, 256, 0, stream>>>(batch, gcnt);
  int nchunk = (NN + 1023) / 1024;
  k_scan1<<<nchunk, 1024, 0, stream>>>(degc, rowptr, aux, dis);
  k_scan2<<<1, 1, 0, stream>>>(aux, auxsc, nchunk);
  k_scan3<<<(NN + 255) / 256, 256, 0, stream>>>(rowptr, auxsc);
  k_fill<<<(NE + 255) / 256, 256, 0, stream>>>(srcv, dstv, rowptr, fillp, colidx);

  int gblk = (NN + 63) / 64;   // 782 blocks ~ 3/CU balanced
  // layer 1 — NEW pair-agg (A/B experiment arm)
  k_wt<<<64, 256, 0, stream>>>(W1, wtb);
  k_gemm<false><<<gblk, 256, 0, stream>>>(x, wtb, nullptr, nullptr, dis, hs);
  k_aggp<<<2048, 256, 0, stream>>>(hs, dis, rowptr, colidx, b1, aggb, stats1);
  k_bnfin<<<1, HD, 0, stream>>>(stats1, g1, be1, scale1, shift1);
  // layer 2 — OLD agg (in-run control)
  k_wt<<<64, 256, 0, stream>>>(W2, wtb);
  k_gemm<true><<<gblk, 256, 0, stream>>>(aggb, wtb, scale1, shift1, dis, hs);
  k_agg<0><<<2048, 256, 0, stream>>>(hs, dis, rowptr, colidx, b2, aggb, stats2,
                                     nullptr, nullptr, nullptr);
  k_bnfin<<<1, HD, 0, stream>>>(stats2, g2, be2, scale2, shift2);
  // layer 3 — OLD agg MODE-1 (pool+linear fused; gcnt hoisted)
  k_wt<<<64, 256, 0, stream>>>(W3, wtb);
  k_gemm<true><<<gblk, 256, 0, stream>>>(aggb, wtb, scale2, shift2, dis, hs);
  k_agg<1><<<2048, 256, 0, stream>>>(hs, dis, rowptr, colidx, b3, nullptr, nullptr,
                                     batch, Wl, gsum);
  k_final<<<1, NGR, 0, stream>>>(gsum, gcnt, bl, out);
}